// Round 1
// baseline (558.243 us; speedup 1.0000x reference)
//
#include <hip/hip_runtime.h>

#define BB 8
#define NN 512
#define PP 32
#define LL 3
#define SLOT (BB*NN*PP)   // 131072 floats

// ---------------------------------------------------------------------------
// K1: for every (layer l, batch b, column j):
//   t31[p][j] = sum_m relu(t4[l][p][1]*w[b][j][m] + Bc_pj*s_m + Cc_pj)
//   base_l[b][j][p] = term1 + sum_q t3[l][p][q]*t31[q][j]
// l==0 additionally: mu0 = relu(base0); tmp2_1[b][j][p] = sum_q t2[1][p][q]*mu0[q][j]
// Block = 256 threads = 8 units(columns) x 32 m-lanes; 2 iterations -> 16 columns.
// Grid = L * B * (N/16) = 768 blocks.
// ---------------------------------------------------------------------------
__global__ __launch_bounds__(256, 2) void k_phaseA(
    const float* __restrict__ x, const float* __restrict__ wts,
    const float* __restrict__ extra, const float* __restrict__ t1,
    const float* __restrict__ t2, const float* __restrict__ t3,
    const float* __restrict__ t4, float* __restrict__ ws)
{
    const int tid = threadIdx.x;
    const int u  = tid >> 5;    // unit (column slot) 0..7
    const int ml = tid & 31;    // m-lane
    const int blk = blockIdx.x;
    const int l  = blk >> 8;          // 0..2
    const int b  = (blk >> 5) & 7;    // 0..7
    const int jt = blk & 31;          // 0..31  (16-column tile)

    __shared__ float red[8][33*32];   // [unit][ml*33 + p], padded: conflict-free
    __shared__ float cbuf[8][33];     // per-unit 32-float exchange

    const float* t4l = t4 + l*(PP*4);
    const float* t3l = t3 + l*(PP*PP);
    const float* t1l = t1 + l*(PP*3);
    const float* xrow = x + b*NN;
    const float* erow = extra + b*NN;

    // s_m for this lane's 16 m-values (m = c*128 + ml*4 + k) — unit-independent
    float4 s4[4];
#pragma unroll
    for (int c = 0; c < 4; ++c) {
        float4 xv = *(const float4*)(xrow + c*128 + ml*4);
        s4[c].x = 2.f*xv.x - 1.f; s4[c].y = 2.f*xv.y - 1.f;
        s4[c].z = 2.f*xv.z - 1.f; s4[c].w = 2.f*xv.w - 1.f;
    }

    for (int iter = 0; iter < 2; ++iter) {
        const int j = jt*16 + iter*8 + u;
        const float* wrow = wts + ((size_t)b*NN + j)*NN;
        float4 w4[4];
#pragma unroll
        for (int c = 0; c < 4; ++c)
            w4[c] = *(const float4*)(wrow + c*128 + ml*4);

        const float xj = xrow[j];
        const float ej = erow[j];
        const float sj = 2.f*xj - 1.f;

        float acc[32];
#pragma unroll
        for (int p = 0; p < 32; ++p) {
            const float4 c4 = *(const float4*)(t4l + p*4);
            const float A  = c4.y;
            const float Bc = -0.5f * c4.z * sj;
            const float Cc = fmaf(c4.x, xj, fmaf(0.5f, c4.z, c4.w));
            float a0 = 0.f, a1 = 0.f;
#pragma unroll
            for (int c = 0; c < 4; ++c) {
                a0 += fmaxf(0.f, fmaf(A, w4[c].x, fmaf(Bc, s4[c].x, Cc)));
                a1 += fmaxf(0.f, fmaf(A, w4[c].y, fmaf(Bc, s4[c].y, Cc)));
                a0 += fmaxf(0.f, fmaf(A, w4[c].z, fmaf(Bc, s4[c].z, Cc)));
                a1 += fmaxf(0.f, fmaf(A, w4[c].w, fmaf(Bc, s4[c].w, Cc)));
            }
            acc[p] = a0 + a1;
        }

        // cross-lane reduction over m (32 lanes), conflict-free padded LDS
#pragma unroll
        for (int p = 0; p < 32; ++p) red[u][ml*33 + p] = acc[p];
        __syncthreads();
        float t31v = 0.f;
#pragma unroll
        for (int k = 0; k < 32; ++k) t31v += red[u][k*33 + ml];
        cbuf[u][ml] = t31v;      // lane ml now owns p = ml; cbuf[u][q] = t31[q][j]
        __syncthreads();

        const int p = ml;
        float term3 = 0.f;
        const float* t3r = t3l + p*32;
#pragma unroll
        for (int q = 0; q < 32; q += 4) {
            float4 tv = *(const float4*)(t3r + q);
            term3 = fmaf(tv.x, cbuf[u][q],   term3);
            term3 = fmaf(tv.y, cbuf[u][q+1], term3);
            term3 = fmaf(tv.z, cbuf[u][q+2], term3);
            term3 = fmaf(tv.w, cbuf[u][q+3], term3);
        }
        const float term1 = fmaf(t1l[p*3], (1.f - xj), fmaf(t1l[p*3+2], ej, t1l[p*3+1]));
        const float basev = term1 + term3;

        if (l == 0) {
            const float mu0 = fmaxf(basev, 0.f);
            __syncthreads();
            cbuf[u][ml] = mu0;
            __syncthreads();
            const float* t2r = t2 + PP*PP + p*32;   // layer-1 t2, row p
            float s0 = 0.f;
#pragma unroll
            for (int q = 0; q < 32; q += 4) {
                float4 tv = *(const float4*)(t2r + q);
                s0 = fmaf(tv.x, cbuf[u][q],   s0);
                s0 = fmaf(tv.y, cbuf[u][q+1], s0);
                s0 = fmaf(tv.z, cbuf[u][q+2], s0);
                s0 = fmaf(tv.w, cbuf[u][q+3], s0);
            }
            ws[2*SLOT + ((size_t)(b*NN + j))*PP + p] = s0;        // tmp2_1 [b][n][p]
        } else {
            float* dst = ws + (l == 1 ? 0 : SLOT);                // base1 / base2
            dst[((size_t)(b*NN + j))*PP + p] = basev;
            __syncthreads();   // keep sync count uniform across l (paranoia; block-uniform anyway)
            __syncthreads();
        }
    }
}

// ---------------------------------------------------------------------------
// K2/K3: mu_l[p][j] = relu(base[b][j][p] + sum_n tmp2in[b][n][p]*adj[b][n][j])
//   !final: tmp2out[b][j][p] = sum_q t2l[p][q]*mu_l[q][j]  (in-place over base, thread-local)
//    final: d_out[b][p][j] = mu_l (LDS transpose for coalesced stores)
// Block = 256 threads = 8 slots x 32 p; each thread owns 2 columns. Grid = B*32.
// ---------------------------------------------------------------------------
__global__ __launch_bounds__(256, 2) void k_layer(
    const float* __restrict__ adj, const float* __restrict__ t2l,
    const float* basein, const float* __restrict__ tmp2in,
    float* tmp2out, float* __restrict__ dout, int final_)
{
    const int tid = threadIdx.x;
    const int p = tid & 31;
    const int slot = tid >> 5;
    const int blk = blockIdx.x;
    const int b  = blk >> 5;
    const int jt = blk & 31;
    const int j0 = jt*16;
    const int ja = j0 + slot*2;

    const float* adjb = adj + (size_t)b*NN*NN + ja;
    const float* tp   = tmp2in + (size_t)b*NN*PP + p;
    float acc0 = basein[((size_t)b*NN + ja)*PP + p];
    float acc1 = basein[((size_t)b*NN + ja + 1)*PP + p];
#pragma unroll 4
    for (int n = 0; n < NN; ++n) {
        const float tv = tp[n*PP];
        const float2 av = *(const float2*)(adjb + (size_t)n*NN);
        acc0 = fmaf(tv, av.x, acc0);
        acc1 = fmaf(tv, av.y, acc1);
    }

    __shared__ float mbuf[16][33];
    mbuf[slot*2][p]     = fmaxf(acc0, 0.f);
    mbuf[slot*2 + 1][p] = fmaxf(acc1, 0.f);
    __syncthreads();

    if (!final_) {
        const float* t2r = t2l + p*32;
        float s0 = 0.f, s1 = 0.f;
#pragma unroll
        for (int q = 0; q < 32; q += 4) {
            float4 tv = *(const float4*)(t2r + q);
            s0 = fmaf(tv.x, mbuf[slot*2][q],   s0);  s1 = fmaf(tv.x, mbuf[slot*2+1][q],   s1);
            s0 = fmaf(tv.y, mbuf[slot*2][q+1], s0);  s1 = fmaf(tv.y, mbuf[slot*2+1][q+1], s1);
            s0 = fmaf(tv.z, mbuf[slot*2][q+2], s0);  s1 = fmaf(tv.z, mbuf[slot*2+1][q+2], s1);
            s0 = fmaf(tv.w, mbuf[slot*2][q+3], s0);  s1 = fmaf(tv.w, mbuf[slot*2+1][q+3], s1);
        }
        tmp2out[((size_t)b*NN + ja)*PP + p]     = s0;
        tmp2out[((size_t)b*NN + ja + 1)*PP + p] = s1;
    } else {
#pragma unroll
        for (int idx = tid; idx < 512; idx += 256) {
            const int pp = idx >> 4, jj = idx & 15;
            dout[((size_t)b*PP + pp)*NN + j0 + jj] = mbuf[jj][pp];
        }
    }
}

extern "C" void kernel_launch(void* const* d_in, const int* in_sizes, int n_in,
                              void* d_out, int out_size, void* d_ws, size_t ws_size,
                              hipStream_t stream) {
    const float* x     = (const float*)d_in[0];
    const float* adj   = (const float*)d_in[1];
    const float* wts   = (const float*)d_in[2];
    const float* extra = (const float*)d_in[3];
    const float* t1    = (const float*)d_in[4];
    const float* t2    = (const float*)d_in[5];
    const float* t3    = (const float*)d_in[6];
    const float* t4    = (const float*)d_in[7];
    float* out = (float*)d_out;
    float* ws  = (float*)d_ws;

    float* slotA = ws;            // base1, later tmp2_2 (in place)
    float* slotB = ws + SLOT;     // base2
    float* slotC = ws + 2*SLOT;   // tmp2_1

    hipLaunchKernelGGL(k_phaseA, dim3(LL*BB*32), dim3(256), 0, stream,
                       x, wts, extra, t1, t2, t3, t4, ws);
    // layer 1: base1 + tmp2_1 @ adj -> mu1 -> tmp2_2 (overwrites slotA)
    hipLaunchKernelGGL(k_layer, dim3(BB*32), dim3(256), 0, stream,
                       adj, t2 + 2*PP*PP, slotA, slotC, slotA, (float*)nullptr, 0);
    // layer 2: base2 + tmp2_2 @ adj -> mu2 -> d_out
    hipLaunchKernelGGL(k_layer, dim3(BB*32), dim3(256), 0, stream,
                       adj, t2, slotB, slotA, (float*)nullptr, out, 1);
}

// Round 2
// 120.489 us; speedup vs baseline: 4.6332x; 4.6332x over previous
//
#include <hip/hip_runtime.h>

#define BB 8
#define NN 512
#define PP 32
#define SLOT (BB*NN*PP)   // 131072 floats

// ---------------------------------------------------------------------------
// K1: block = (layer l, batch b, 8-row tile). 256 thr = 8 rows x 32 p.
//  t31[p][n] = sum_m relu(t4[p,1]*w[n,m] + (-0.5 t4[p,2] s_n)*s_m
//                         + (t4[p,0]x_n + 0.5 t4[p,2] + t4[p,3]))
//  base_l[n][p] = term1 + sum_q t3[p][q] t31[q][n]
//  l==0: mu0=relu(base0); tmp2_1[n][p] = sum_q t2[1][p][q] mu0[q][n]
// Scalar accumulator per thread -> no spills. w,s staged in LDS (broadcast).
// ---------------------------------------------------------------------------
__global__ __launch_bounds__(256) void k_phaseA(
    const float* __restrict__ x, const float* __restrict__ wts,
    const float* __restrict__ extra, const float* __restrict__ t1,
    const float* __restrict__ t2, const float* __restrict__ t3,
    const float* __restrict__ t4, float* __restrict__ ws)
{
    const int tid = threadIdx.x;
    const int blk = blockIdx.x;
    const int l  = blk >> 9;          // 0..2
    const int b  = (blk >> 6) & 7;    // 0..7
    const int nt = blk & 63;          // 0..63
    const int n0 = nt * 8;
    const int w  = tid >> 6;
    const int lane = tid & 63;
    const int h  = lane >> 5;
    const int p  = lane & 31;
    const int r  = w*2 + h;           // row slot 0..7
    const int n  = n0 + r;

    __shared__ float wlds[8][516];    // pad 4: rows start 4 banks apart, 16B-aligned
    __shared__ float slds[516];
    __shared__ float ex[8][33];

    const float* xrow  = x + b*NN;
    const float* wbase = wts + ((size_t)b*NN + n0)*NN;
#pragma unroll
    for (int k = 0; k < 4; ++k) {
        int f = k*256 + tid;
        int row = f >> 7, c4 = f & 127;
        float4 v = *(const float4*)(wbase + (size_t)row*NN + c4*4);
        *(float4*)&wlds[row][c4*4] = v;
    }
    if (tid < 128) {
        float4 xv = *(const float4*)(xrow + tid*4);
        float4 sv = { 2.f*xv.x-1.f, 2.f*xv.y-1.f, 2.f*xv.z-1.f, 2.f*xv.w-1.f };
        *(float4*)&slds[tid*4] = sv;
    }
    __syncthreads();

    const float* t4l = t4 + l*(PP*4);
    const float4 c4v = *(const float4*)(t4l + p*4);
    const float xj = xrow[n];
    const float ej = extra[b*NN + n];
    const float sj = 2.f*xj - 1.f;
    const float A  = c4v.y;
    const float Bc = -0.5f * c4v.z * sj;
    const float Cc = fmaf(c4v.x, xj, fmaf(0.5f, c4v.z, c4v.w));

    float acc = 0.f;
#pragma unroll 8
    for (int mc = 0; mc < 128; ++mc) {
        float4 wv = *(const float4*)&wlds[r][mc*4];
        float4 sv = *(const float4*)&slds[mc*4];
        acc += fmaxf(0.f, fmaf(A, wv.x, fmaf(Bc, sv.x, Cc)));
        acc += fmaxf(0.f, fmaf(A, wv.y, fmaf(Bc, sv.y, Cc)));
        acc += fmaxf(0.f, fmaf(A, wv.z, fmaf(Bc, sv.z, Cc)));
        acc += fmaxf(0.f, fmaf(A, wv.w, fmaf(Bc, sv.w, Cc)));
    }
    ex[r][p] = acc;           // t31[p][n]
    __syncthreads();

    const float* t3r = t3 + l*(PP*PP) + p*32;
    float term3 = 0.f;
#pragma unroll
    for (int q = 0; q < 32; q += 4) {
        float4 tv = *(const float4*)(t3r + q);
        term3 = fmaf(tv.x, ex[r][q],   term3);
        term3 = fmaf(tv.y, ex[r][q+1], term3);
        term3 = fmaf(tv.z, ex[r][q+2], term3);
        term3 = fmaf(tv.w, ex[r][q+3], term3);
    }
    const float* t1l = t1 + l*(PP*3);
    const float term1 = fmaf(t1l[p*3], 1.f-xj, fmaf(t1l[p*3+2], ej, t1l[p*3+1]));
    const float basev = term1 + term3;

    if (l == 0) {
        __syncthreads();
        ex[r][p] = fmaxf(basev, 0.f);   // mu0
        __syncthreads();
        const float* t2r = t2 + PP*PP + p*32;   // layer-1 t2
        float s0 = 0.f;
#pragma unroll
        for (int q = 0; q < 32; q += 4) {
            float4 tv = *(const float4*)(t2r + q);
            s0 = fmaf(tv.x, ex[r][q],   s0);
            s0 = fmaf(tv.y, ex[r][q+1], s0);
            s0 = fmaf(tv.z, ex[r][q+2], s0);
            s0 = fmaf(tv.w, ex[r][q+3], s0);
        }
        ws[2*SLOT + ((size_t)(b*NN + n))*PP + p] = s0;   // tmp2_1
    } else {
        float* dst = ws + (l == 1 ? 0 : SLOT);           // base1 / base2
        dst[((size_t)(b*NN + n))*PP + p] = basev;
    }
}

// ---------------------------------------------------------------------------
// K2/K3: block = (b, 32-col tile). 256 thr = 4 waves; half-wave (32 lanes=j)
// owns n-chunk c = wave*2+h of 64 rows. Coalesced adj reads (row-major).
// tmp2 chunk staged in LDS. Partials reduced via LDS, relu, then either
// tmp2out = t2l * mu (LDS transpose, coalesced store) or d_out[b][p][j].
// ---------------------------------------------------------------------------
__global__ __launch_bounds__(256) void k_layer(
    const float* __restrict__ adj, const float* __restrict__ t2l,
    const float* __restrict__ basein, const float* __restrict__ tmp2in,
    float* __restrict__ tmp2out, float* __restrict__ dout, int final_)
{
    const int tid = threadIdx.x;
    const int b  = blockIdx.x >> 4;
    const int jt = blockIdx.x & 15;
    const int j0 = jt * 32;
    const int wv = tid >> 6;
    const int lane = tid & 63;
    const int h  = lane >> 5;
    const int jl = lane & 31;
    const int c  = wv*2 + h;          // n-chunk 0..7 (64 rows each)

    __shared__ float tst[8*2048];     // 64KB: tmp2 staging, then partials/tbuf
    __shared__ float xbuf[32*33];     // mu exchange [p][j], padded

    {   // stage tmp2[b][c*64 .. c*64+64)[0..32) : contiguous 8KB per chunk
        const float* src = tmp2in + ((size_t)b*NN + c*64)*PP;
        float* dst = tst + c*2048;
#pragma unroll
        for (int t = 0; t < 16; ++t) {
            float4 v = *(const float4*)(src + t*128 + jl*4);
            *(float4*)(dst + t*128 + jl*4) = v;
        }
    }
    __syncthreads();

    float acc[32];
#pragma unroll
    for (int p = 0; p < 32; ++p) acc[p] = 0.f;

    const float* adjc = adj + ((size_t)b*NN + c*64)*NN + j0 + jl;
    const float* trow = tst + c*2048;
    for (int i = 0; i < 64; ++i) {
        float av = adjc[(size_t)i*NN];
#pragma unroll
        for (int pq = 0; pq < 8; ++pq) {
            float4 tv = *(const float4*)(trow + i*32 + pq*4);
            acc[pq*4+0] = fmaf(tv.x, av, acc[pq*4+0]);
            acc[pq*4+1] = fmaf(tv.y, av, acc[pq*4+1]);
            acc[pq*4+2] = fmaf(tv.z, av, acc[pq*4+2]);
            acc[pq*4+3] = fmaf(tv.w, av, acc[pq*4+3]);
        }
    }
    __syncthreads();   // everyone done reading staged tmp2

    // partials: part[(c*32+jl)*36 + p]  (stride 36 keeps 16B alignment)
    float* part = tst;
#pragma unroll
    for (int p4 = 0; p4 < 8; ++p4) {
        float4 v = { acc[p4*4], acc[p4*4+1], acc[p4*4+2], acc[p4*4+3] };
        *(float4*)(part + (c*32 + jl)*36 + p4*4) = v;
    }
    __syncthreads();

    // reduce: thread -> (j = tid&31, pg = tid>>5) owns p = pg*4..pg*4+3
    const int j  = tid & 31;
    const int pg = tid >> 5;
    float4 s = *(const float4*)(basein + ((size_t)b*NN + j0 + j)*PP + pg*4);
    float r0=s.x, r1=s.y, r2=s.z, r3=s.w;
#pragma unroll
    for (int cc = 0; cc < 8; ++cc) {
        float4 v = *(const float4*)(part + (cc*32 + j)*36 + pg*4);
        r0 += v.x; r1 += v.y; r2 += v.z; r3 += v.w;
    }
    r0 = fmaxf(r0, 0.f); r1 = fmaxf(r1, 0.f); r2 = fmaxf(r2, 0.f); r3 = fmaxf(r3, 0.f);

    if (final_) {
        float* dp = dout + ((size_t)b*PP + pg*4)*NN + j0 + j;
        dp[0]      = r0;
        dp[NN]     = r1;
        dp[2*NN]   = r2;
        dp[3*(size_t)NN] = r3;
    } else {
        xbuf[(pg*4+0)*33 + j] = r0;
        xbuf[(pg*4+1)*33 + j] = r1;
        xbuf[(pg*4+2)*33 + j] = r2;
        xbuf[(pg*4+3)*33 + j] = r3;
        __syncthreads();   // also guarantees all 'part' reads done before tbuf reuse

        float o0=0.f, o1=0.f, o2=0.f, o3=0.f;
        const float* tr0 = t2l + (pg*4+0)*32;
        const float* tr1 = t2l + (pg*4+1)*32;
        const float* tr2 = t2l + (pg*4+2)*32;
        const float* tr3 = t2l + (pg*4+3)*32;
#pragma unroll
        for (int qc = 0; qc < 8; ++qc) {
            float m0 = xbuf[(qc*4+0)*33 + j];
            float m1 = xbuf[(qc*4+1)*33 + j];
            float m2 = xbuf[(qc*4+2)*33 + j];
            float m3 = xbuf[(qc*4+3)*33 + j];
            float4 a0 = *(const float4*)(tr0 + qc*4);
            float4 a1 = *(const float4*)(tr1 + qc*4);
            float4 a2 = *(const float4*)(tr2 + qc*4);
            float4 a3 = *(const float4*)(tr3 + qc*4);
            o0 = fmaf(a0.x,m0,fmaf(a0.y,m1,fmaf(a0.z,m2,fmaf(a0.w,m3,o0))));
            o1 = fmaf(a1.x,m0,fmaf(a1.y,m1,fmaf(a1.z,m2,fmaf(a1.w,m3,o1))));
            o2 = fmaf(a2.x,m0,fmaf(a2.y,m1,fmaf(a2.z,m2,fmaf(a2.w,m3,o2))));
            o3 = fmaf(a3.x,m0,fmaf(a3.y,m1,fmaf(a3.z,m2,fmaf(a3.w,m3,o3))));
        }
        // transpose via LDS (stride 40, 16B-aligned) -> coalesced float4 store
        float4 ov = { o0, o1, o2, o3 };
        *(float4*)(tst + j*40 + pg*4) = ov;
        __syncthreads();
        const int jj = tid >> 3;            // element (j0+jj, pp..pp+3)
        const int pp = (tid & 7) * 4;
        float4 sv = *(const float4*)(tst + jj*40 + pp);
        *(float4*)(tmp2out + ((size_t)b*NN + j0)*PP + tid*4) = sv;
    }
}

extern "C" void kernel_launch(void* const* d_in, const int* in_sizes, int n_in,
                              void* d_out, int out_size, void* d_ws, size_t ws_size,
                              hipStream_t stream) {
    const float* x     = (const float*)d_in[0];
    const float* adj   = (const float*)d_in[1];
    const float* wts   = (const float*)d_in[2];
    const float* extra = (const float*)d_in[3];
    const float* t1    = (const float*)d_in[4];
    const float* t2    = (const float*)d_in[5];
    const float* t3    = (const float*)d_in[6];
    const float* t4    = (const float*)d_in[7];
    float* out = (float*)d_out;
    float* ws  = (float*)d_ws;

    float* slotA = ws;            // base1, then tmp2_2 (in place, same block/tile)
    float* slotB = ws + SLOT;     // base2
    float* slotC = ws + 2*SLOT;   // tmp2_1

    hipLaunchKernelGGL(k_phaseA, dim3(3*BB*64), dim3(256), 0, stream,
                       x, wts, extra, t1, t2, t3, t4, ws);
    // layer 1: mu1 = relu(base1 + tmp2_1 @ adj); tmp2_2 = t2[2]*mu1 -> slotA
    hipLaunchKernelGGL(k_layer, dim3(BB*16), dim3(256), 0, stream,
                       adj, t2 + 2*PP*PP, slotA, slotC, slotA, (float*)nullptr, 0);
    // layer 2: mu2 = relu(base2 + tmp2_2 @ adj) -> d_out (transposed store)
    hipLaunchKernelGGL(k_layer, dim3(BB*16), dim3(256), 0, stream,
                       adj, t2, slotB, slotA, (float*)nullptr, out, 1);
}